// Round 5
// baseline (1153.465 us; speedup 1.0000x reference)
//
#include <hip/hip_runtime.h>
#include <stdint.h>

typedef __bf16 bf16;
typedef __bf16 bf16x4 __attribute__((ext_vector_type(4)));
typedef __bf16 bf16x8 __attribute__((ext_vector_type(8)));
typedef float  f32x4  __attribute__((ext_vector_type(4)));
typedef float  fvec4  __attribute__((ext_vector_type(4)));

#define B_DIM 16384
#define H_DIM 1024
#define K_DIM 2048
#define NKT   32      // K_DIM / 64 K-tiles

// ---- async global->LDS, 16B per lane ----
__device__ __forceinline__ void g2l16(const void* g, void* l) {
    __builtin_amdgcn_global_load_lds(
        (const __attribute__((address_space(1))) void*)g,
        (__attribute__((address_space(3))) void*)l,
        16, 0, 0);
}

__device__ __forceinline__ float sigm_fast(float x) {
    x = fminf(fmaxf(x, -40.f), 40.f);
    float e = __builtin_amdgcn_exp2f(-1.4426950408889634f * x);
    return __builtin_amdgcn_rcpf(1.0f + e);
}
__device__ __forceinline__ float tanh_fast(float x) {
    x = fminf(fmaxf(x, -40.f), 40.f);
    float e = __builtin_amdgcn_exp2f(-2.8853900817779268f * x);   // exp(-2x)
    return (1.0f - e) * __builtin_amdgcn_rcpf(1.0f + e);
}

// ---- streaming convert (UNCHANGED from round 4: dense 16B/lane loads) ----
// Note: cvt duration proved insensitive to implementation (residual ~234us
// constant across NT-strided and dense versions) -> not impl-bound; leave it.
__global__ __launch_bounds__(256) void cvt_all(const float* __restrict__ x,
                                               const float* __restrict__ h,
                                               const float* __restrict__ Wx,
                                               const float* __restrict__ Rh,
                                               const float* __restrict__ bx,
                                               const float* __restrict__ bh,
                                               bf16* __restrict__ U,
                                               bf16* __restrict__ W,
                                               float* __restrict__ bb) {
    const int b   = blockIdx.x;          // 0..10239
    const int tid = threadIdx.x;
    const float* src;
    bf16* dst;
    int half, blk;
    if (b < 8192) {                      // x / h  -> U (16384 rows)
        src  = (b < 4096) ? x : h;
        half = (b < 4096) ? 0 : 1024;
        dst  = U;
        blk  = b & 4095;
    } else {                             // Wx / Rh -> W (4096 rows)
        int wb = b - 8192;
        src  = (wb < 1024) ? Wx : Rh;
        half = (wb < 1024) ? 0 : 1024;
        dst  = W;
        blk  = wb & 1023;
    }
    const float* s0 = src + (((size_t)blk << 2) << 10) + (tid << 2);
    bf16*        d0 = dst + (((size_t)blk << 2) << 11) + half + (tid << 2);
#pragma unroll
    for (int u = 0; u < 4; ++u) {
        fvec4 v = *(const fvec4*)(s0 + (u << 10));
        bf16x4 o = {(bf16)v.x, (bf16)v.y, (bf16)v.z, (bf16)v.w};
        *(bf16x4*)(d0 + (u << 11)) = o;
    }
    if (b == 0) {
        for (int i = tid; i < 4096; i += 256) bb[i] = bx[i] + bh[i];
    }
}

// ---- fused GEMM (pre = U.W^T + bb) + LSTM epilogue ----
// v3 geometry: 256x256 block, BK=64, FOUR waves (2M x 2N), per-wave 128x128
// (acc[8][8] f32x4 = 256 regs -> 1 wave/SIMD, __launch_bounds__(256,1)).
// Rationale: symmetric 8x frag reuse cuts LDS reads to 128 b128/kt/CU (-33%
// vs 8-wave 2Mx4N), and 64 independent MFMAs per k-slice give one wave
// enough ILP to keep its MFMA pipe fed while the compiler interleaves the
// 32 frag reads with counted lgkm waits (no barrier between reads & MFMA).
// B tile row r -> gate (r>>4)&3, h_local (r>>6)*16+(r&15): for acc[mi][ni],
// out col br=(wn<<7)+(ni<<4)+lc => gate=ni&3, h=h0+16*((wn<<1)+(ni>>2))+lc
// -> lane-local LSTM epilogue (all 4 gates in-lane).
// LDS: As/Bs[2 dbuf][256x64] = 128 KiB; XOR chunk-swizzle c^(row&7) via
// pre-swizzled GLOBAL source (global_load_lds dest must be linear;
// SQ_LDS_BANK_CONFLICT == 0 verified for this read pattern in r3/r4).
//
// Schedule per kt (2 barriers, counted vmcnt, 1 K-tile always in flight):
//   BAR1  (all waves done reading buf^1 in kt-1 -> safe to overwrite)
//   stage kt+1 -> buf^1   (16 g2l16/thread)          [kt<31]
//   vmcnt(16)  (kt's 16 loads landed; kt+1's stay in flight; NEVER 0 mid-loop)
//   BAR2  (collective: buf fully staged)
//   compute buf: 2 ks-slices x {16 ds_read_b128 + 64 MFMA}, compiler-scheduled
// RAW: stage(kt) drained at kt's vmcnt(16)+BAR2 before compute(kt) reads it.
// WAR: compute(kt-1)'s reads completed (data consumed) before BAR1(kt).
// Stage-latency cover: issued kt step2, waited kt+1 step3 = one full compute
// window (~2500 cyc) >> 900-cyc HBM miss. Tail: kt==31 stages nothing, vmcnt(0).
__global__ __launch_bounds__(256, 1)
void lstm_fused(const bf16* __restrict__ U, const bf16* __restrict__ W,
                const float* __restrict__ bb, const float* __restrict__ cprev,
                float* __restrict__ out) {
    __shared__ __align__(16) bf16 As[2][256 * 64];
    __shared__ __align__(16) bf16 Bs[2][256 * 64];

    const int tid  = threadIdx.x;
    const int wave = tid >> 6;
    const int lane = tid & 63;
    const int quad = lane >> 4;
    const int lc   = lane & 15;
    const int wm   = wave >> 1;          // 0..1  (M half, 128 rows)
    const int wn   = wave & 1;           // 0..1  (N half, 128 cols)

    // XCD-aware mapping: 1024 blocks, 8 XCDs x 128. Each XCD owns 2 h-slices
    // and sweeps all 64 m-tiles -> B panel hot in XCD-L2, U shared via L3.
    int bid   = blockIdx.x;
    int xcd   = bid & 7;
    int t     = bid >> 3;                // 0..127
    int h_idx = (xcd << 1) + (t >> 6);   // 0..15
    int m_idx = t & 63;                  // 0..63
    const int m0 = m_idx << 8;           // 256 U-rows per tile
    const int h0 = h_idx << 6;           // 64 h per tile

    // ---- per-thread staging addresses (32-bit offsets: U=64MiB, W=16MiB) ----
    // half-tile = 128 rows x 64 cols bf16 = 16KB = 256 thr x 4 x 16B.
    // slot = ld*256+tid (ld 0..3); LDS dest linear slot*16; global col chunk
    // pre-swizzled: chunk ^ (row&7).
    uint32_t offA[4][2], offB[4][2];     // [ld][half]
    uint32_t lofs[4];
#pragma unroll
    for (int ld = 0; ld < 4; ++ld) {
        int slot  = (ld << 8) + tid;     // 0..1023
        int row   = slot >> 3;           // 0..127 within half
        int chunk = slot & 7;
        int colb  = (chunk ^ (row & 7)) << 4;
        lofs[ld]  = slot << 4;
#pragma unroll
        for (int hf = 0; hf < 2; ++hf) {
            int arow = m0 + (hf << 7) + row;
            offA[ld][hf] = ((uint32_t)arow << 12) + colb;
            int br   = (hf << 7) + row;                    // B tile row 0..255
            int gate = (br >> 4) & 3;
            int hl   = ((br >> 6) << 4) + (br & 15);
            int wrow = (gate << 10) + h0 + hl;
            offB[ld][hf] = ((uint32_t)wrow << 12) + colb;
        }
    }
    const char* Ub = (const char*)U;     // row stride 4096 B
    const char* Wb = (const char*)W;     // row stride 4096 B
    char* AsB = (char*)As;
    char* BsB = (char*)Bs;

// stage one full K-tile (A 32KB + B 32KB) into dbuf: 16 g2l16/thread
#define STG_ALL(dbuf, ktt) do {                                                \
        _Pragma("unroll")                                                      \
        for (int hf = 0; hf < 2; ++hf)                                         \
            _Pragma("unroll")                                                  \
            for (int ld = 0; ld < 4; ++ld)                                     \
                g2l16(Ub + offA[ld][hf] + ((ktt) << 7),                        \
                      AsB + ((dbuf) << 15) + (hf << 14) + lofs[ld]);           \
        _Pragma("unroll")                                                      \
        for (int hf = 0; hf < 2; ++hf)                                         \
            _Pragma("unroll")                                                  \
            for (int ld = 0; ld < 4; ++ld)                                     \
                g2l16(Wb + offB[ld][hf] + ((ktt) << 7),                        \
                      BsB + ((dbuf) << 15) + (hf << 14) + lofs[ld]);           \
    } while (0)

// fragment read: global chunk (ks*4+quad), swizzled by row&7 == lc&7
#define LDFRAG(BASEB, dbuf, row, ks)                                           \
    (*(const bf16x8*)((BASEB) + ((dbuf) << 15) + ((row) << 7) +                \
                      ((((((ks) << 2)) + quad) ^ (lc & 7)) << 4)))

    f32x4 acc[8][8];
#pragma unroll
    for (int mi = 0; mi < 8; ++mi)
#pragma unroll
        for (int ni = 0; ni < 8; ++ni)
            acc[mi][ni] = (f32x4){0.f, 0.f, 0.f, 0.f};

    // ---- prologue: stage kt0 into buf0 (16 loads, cold; one-time cost) ----
    STG_ALL(0, 0);

    const int rA0 = (wm << 7) + lc;      // A row base
    const int rB0 = (wn << 7) + lc;      // B row base

#pragma clang loop unroll(disable)
    for (int kt = 0; kt < NKT; ++kt) {
        const int buf = kt & 1;

        __builtin_amdgcn_s_barrier();            // buf^1 readers done
        if (kt < NKT - 1) STG_ALL(buf ^ 1, kt + 1);
        if (kt < NKT - 1) {
            asm volatile("s_waitcnt vmcnt(16)" ::: "memory");   // kt landed
        } else {
            asm volatile("s_waitcnt vmcnt(0)" ::: "memory");
        }
        __builtin_amdgcn_s_barrier();            // collective: buf staged

#pragma unroll
        for (int ks = 0; ks < 2; ++ks) {
            bf16x8 a_[8], b_[8];
#pragma unroll
            for (int mi = 0; mi < 8; ++mi)
                a_[mi] = LDFRAG(AsB, buf, rA0 + (mi << 4), ks);
#pragma unroll
            for (int ni = 0; ni < 8; ++ni)
                b_[ni] = LDFRAG(BsB, buf, rB0 + (ni << 4), ks);
#pragma unroll
            for (int mi = 0; mi < 8; ++mi)
#pragma unroll
                for (int ni = 0; ni < 8; ++ni)
                    acc[mi][ni] = __builtin_amdgcn_mfma_f32_16x16x32_bf16(
                        a_[mi], b_[ni], acc[mi][ni], 0, 0, 0);
        }
    }

    // ---- LSTM epilogue: C/D layout col=lane&15, row=quad*4+reg ----
    // acc[mi][ni]: gate = ni&3, h-group = ni>>2 -> all 4 gates lane-local.
    const int hb = h0 + (wn << 5) + lc;
    float bias[2][4];
#pragma unroll
    for (int hg = 0; hg < 2; ++hg)
#pragma unroll
        for (int g = 0; g < 4; ++g)
            bias[hg][g] = bb[(g << 10) + hb + (hg << 4)];

    float* out_h = out;
    float* out_c = out + (size_t)B_DIM * H_DIM;
#pragma unroll
    for (int mi = 0; mi < 8; ++mi) {
#pragma unroll
        for (int r = 0; r < 4; ++r) {
            int brow  = m0 + (wm << 7) + (mi << 4) + (quad << 2) + r;
            size_t rb = (size_t)brow << 10;
#pragma unroll
            for (int hg = 0; hg < 2; ++hg) {
                const int h = hb + (hg << 4);
                float zp = acc[mi][(hg << 2) + 0][r] + bias[hg][0];
                float ip = acc[mi][(hg << 2) + 1][r] + bias[hg][1];
                float fp = acc[mi][(hg << 2) + 2][r] + bias[hg][2];
                float op = acc[mi][(hg << 2) + 3][r] + bias[hg][3];
                float zz = tanh_fast(zp);
                float ii = sigm_fast(ip);
                float ff = sigm_fast(fp);
                float oo = sigm_fast(op);
                float cp = cprev[rb + h];
                float cn = ff * cp + ii * zz;
                float hn = oo * tanh_fast(cn);
                out_h[rb + h] = hn;
                out_c[rb + h] = cn;
            }
        }
    }
}

extern "C" void kernel_launch(void* const* d_in, const int* in_sizes, int n_in,
                              void* d_out, int out_size, void* d_ws, size_t ws_size,
                              hipStream_t stream) {
    const float* x  = (const float*)d_in[0];
    const float* hp = (const float*)d_in[1];
    const float* cp = (const float*)d_in[2];
    const float* Wx = (const float*)d_in[3];
    const float* bx = (const float*)d_in[4];
    const float* Rh = (const float*)d_in[5];
    const float* bh = (const float*)d_in[6];

    // workspace: U 64 MiB | W 16 MiB | bb 16 KiB
    bf16*  U  = (bf16*)d_ws;
    bf16*  W  = (bf16*)((char*)d_ws + (size_t)67108864);
    float* bb = (float*)((char*)d_ws + (size_t)67108864 + 16777216);

    cvt_all<<<10240, 256, 0, stream>>>(x, hp, Wx, Rh, bx, bh, U, W, bb);
    lstm_fused<<<1024, 256, 0, stream>>>(U, W, bb, cp, (float*)d_out);
}